// Round 10
// baseline (181.463 us; speedup 1.0000x reference)
//
#include <hip/hip_runtime.h>

#define D 32
#define RANGE 128        // nodes per range; R = ceil(n/RANGE) = 782
#define RMAX 800         // LDS counter capacity for coarse passes
#define JC 512           // edge chunks for count/reorder passes
#define SCAN_CHUNK 4096  // scan: 256 threads x 16 elems
#define CAP 4096         // LDS sorted-record capacity per range (padded mean ~2816)
#define PAD_D 4          // dst segment pad: 4 x 8B = 32B sectors
#define PAD_S 8          // src segment pad: 8 x 4B = 32B sectors

// ---- K1: per-(range,chunk) coarse counts, rounded up to sector multiples. ----
__global__ __launch_bounds__(512) void count_kernel(
        const int* __restrict__ src, const int* __restrict__ dst,
        int* __restrict__ cnt, int E, int R, int chunk) {
    __shared__ int cd[RMAX];
    __shared__ int cs[RMAX];
    int j = blockIdx.x;
    for (int i = threadIdx.x; i < R; i += blockDim.x) { cd[i] = 0; cs[i] = 0; }
    __syncthreads();
    int e0 = j * chunk, e1 = min(E, e0 + chunk);
    for (int e = e0 + 2 * threadIdx.x; e < e1; e += 2 * blockDim.x) {
        if (e + 1 < e1) {
            int2 s2 = *(const int2*)(src + e);
            int2 d2 = *(const int2*)(dst + e);
            atomicAdd(&cd[d2.x >> 7], 1);
            atomicAdd(&cd[d2.y >> 7], 1);
            atomicAdd(&cs[s2.x >> 7], 1);
            atomicAdd(&cs[s2.y >> 7], 1);
        } else {
            atomicAdd(&cd[dst[e] >> 7], 1);
            atomicAdd(&cs[src[e] >> 7], 1);
        }
    }
    __syncthreads();
    // padded counts -> scan yields 32B-aligned segment starts
    for (int i = threadIdx.x; i < R; i += blockDim.x) {
        cnt[(size_t)i * JC + j]       = (cd[i] + (PAD_D - 1)) & ~(PAD_D - 1);
        cnt[(size_t)(R + i) * JC + j] = (cs[i] + (PAD_S - 1)) & ~(PAD_S - 1);
    }
    if (j == 0 && threadIdx.x == 0) cnt[(size_t)2 * R * JC] = 0;  // grand-total slot
}

// ---- hierarchical exclusive scan over 2*R*JC+1 counts ----
__global__ void scan_part(const int* __restrict__ deg, int* __restrict__ offsets,
                          int* __restrict__ blockSums, int n) {
    __shared__ int lds[256];
    int t = threadIdx.x;
    int base = blockIdx.x * SCAN_CHUNK + t * 16;
    int v[16];
    int tsum = 0;
#pragma unroll
    for (int i = 0; i < 16; i++) {
        int idx = base + i;
        int x = (idx < n) ? deg[idx] : 0;
        v[i] = tsum;
        tsum += x;
    }
    lds[t] = tsum;
    __syncthreads();
    for (int off = 1; off < 256; off <<= 1) {
        int val = (t >= off) ? lds[t - off] : 0;
        __syncthreads();
        lds[t] += val;
        __syncthreads();
    }
    int texcl = (t == 0) ? 0 : lds[t - 1];
    if (t == 255) blockSums[blockIdx.x] = lds[255];
#pragma unroll
    for (int i = 0; i < 16; i++) {
        int idx = base + i;
        if (idx < n) offsets[idx] = texcl + v[i];
    }
}

__global__ void scan_top(int* __restrict__ blockSums, int nb) {
    __shared__ int lds[256];
    int t = threadIdx.x;
    lds[t] = (t < nb) ? blockSums[t] : 0;
    __syncthreads();
    for (int off = 1; off < 256; off <<= 1) {
        int val = (t >= off) ? lds[t - off] : 0;
        __syncthreads();
        lds[t] += val;
        __syncthreads();
    }
    if (t < nb) blockSums[t] = (t == 0) ? 0 : lds[t - 1];
}

__global__ void scan_add(int* __restrict__ offsets, const int* __restrict__ blockSums, int n) {
    int i = blockIdx.x * blockDim.x + threadIdx.x;
    if (i < n) offsets[i] += blockSums[i / SCAN_CHUNK];
}

// ---- K2: fused reorder into 32B-aligned segments + tail-pad with dummies. ----
// dst rec = (s | dl<<17, ef_masked); dummy = (511<<17, 0). src rec = s; dummy = ~0u.
__global__ __launch_bounds__(512) void reorder_kernel(
        const int* __restrict__ src, const int* __restrict__ dst,
        const float* __restrict__ ef, const int* __restrict__ offs,
        unsigned int* __restrict__ recsS, uint2* __restrict__ recs,
        int E, int R, int chunk) {
    __shared__ int curD[RMAX];
    __shared__ int curS[RMAX];
    int j = blockIdx.x;
    int srcBase = offs[(size_t)R * JC];   // src stream rebased to recsS[0]
    for (int i = threadIdx.x; i < R; i += blockDim.x) {
        curD[i] = offs[(size_t)i * JC + j];
        curS[i] = offs[(size_t)(R + i) * JC + j] - srcBase;
    }
    __syncthreads();
    int e0 = j * chunk, e1 = min(E, e0 + chunk);
    for (int e = e0 + 2 * threadIdx.x; e < e1; e += 2 * blockDim.x) {
        if (e + 1 < e1) {
            int2 s2 = *(const int2*)(src + e);
            int2 d2 = *(const int2*)(dst + e);
            float2 w2 = *(const float2*)(ef + e);
            int ps0 = atomicAdd(&curS[s2.x >> 7], 1);
            int ps1 = atomicAdd(&curS[s2.y >> 7], 1);
            recsS[ps0] = (unsigned)s2.x;
            recsS[ps1] = (unsigned)s2.y;
            float w0 = (s2.x == d2.x) ? 0.0f : w2.x;
            float w1 = (s2.y == d2.y) ? 0.0f : w2.y;
            int pd0 = atomicAdd(&curD[d2.x >> 7], 1);
            int pd1 = atomicAdd(&curD[d2.y >> 7], 1);
            recs[pd0] = make_uint2((unsigned)s2.x | ((unsigned)(d2.x & (RANGE - 1)) << 17),
                                   __float_as_uint(w0));
            recs[pd1] = make_uint2((unsigned)s2.y | ((unsigned)(d2.y & (RANGE - 1)) << 17),
                                   __float_as_uint(w1));
        } else {
            int s = src[e], d = dst[e];
            int ps = atomicAdd(&curS[s >> 7], 1);
            recsS[ps] = (unsigned)s;
            float w = (s == d) ? 0.0f : ef[e];
            int pd = atomicAdd(&curD[d >> 7], 1);
            recs[pd] = make_uint2((unsigned)s | ((unsigned)(d & (RANGE - 1)) << 17),
                                  __float_as_uint(w));
        }
    }
    __syncthreads();
    // pad each segment tail to its aligned end (scan guaranteed room)
    for (int i = threadIdx.x; i < R; i += blockDim.x) {
        int initD = offs[(size_t)i * JC + j];
        int finD = curD[i];
        int endD = initD + ((finD - initD + (PAD_D - 1)) & ~(PAD_D - 1));
        for (int k = finD; k < endD; k++) recs[k] = make_uint2(511u << 17, 0u);
        int initS = offs[(size_t)(R + i) * JC + j] - srcBase;
        int finS = curS[i];
        int endS = initS + ((finS - initS + (PAD_S - 1)) & ~(PAD_S - 1));
        for (int k = finS; k < endS; k++) recsS[k] = 0xFFFFFFFFu;
    }
}

// ---- K3: fused out-degree count + pre-scaled bf16 feature rows. ----
__device__ __forceinline__ unsigned short f2bf(float x) {
    unsigned u = __float_as_uint(x);
    u += 0x7FFFu + ((u >> 16) & 1u);
    return (unsigned short)(u >> 16);
}

__global__ void srcnorm_convert(const unsigned int* __restrict__ recsS,
                                const int* __restrict__ offs, const float* __restrict__ feat,
                                unsigned short* __restrict__ featb, int E, int n, int R) {
    __shared__ int cnt[RANGE];
    int r = blockIdx.x;
    int base = r * RANGE;
    int lim = min(n - base, RANGE);
    for (int i = threadIdx.x; i < RANGE; i += blockDim.x) cnt[i] = 0;
    __syncthreads();
    int srcBase = offs[(size_t)R * JC];
    int start = offs[(size_t)(R + r) * JC] - srcBase;
    int end = ((r + 1 < R) ? offs[(size_t)(R + r + 1) * JC]
                           : offs[(size_t)2 * R * JC]) - srcBase;
    for (int i = start + threadIdx.x; i < end; i += blockDim.x) {
        unsigned idx = recsS[i] - (unsigned)base;
        if (idx < (unsigned)lim) atomicAdd(&cnt[idx], 1);   // dummies skipped
    }
    __syncthreads();
    int total4 = lim * 8;   // 8 float4 chunks per row
    for (int i = threadIdx.x; i < total4; i += blockDim.x) {
        int row = i >> 3;
        float sn = rsqrtf((float)max(cnt[row], 1));
        float4 f = ((const float4*)(feat + (size_t)(base + row) * D))[i & 7];
        ushort4 u;
        u.x = f2bf(f.x * sn); u.y = f2bf(f.y * sn);
        u.z = f2bf(f.z * sn); u.w = f2bf(f.w * sn);
        ((ushort4*)(featb + (size_t)(base + row) * D))[i & 7] = u;
    }
}

// ---- K4: per-range counting sort in LDS + per-node register gather + output. ----
__global__ __launch_bounds__(512) void gather_kernel(
        const float* __restrict__ feat, const unsigned short* __restrict__ featb,
        const uint2* __restrict__ recs, const int* __restrict__ offs,
        float* __restrict__ out, int E, int n, int R) {
    __shared__ uint2 srec[CAP];          // 32 KB sorted records
    __shared__ int indeg[RANGE];
    __shared__ int pre[RANGE + 1];
    __shared__ int cur[RANGE];
    int r = blockIdx.x;
    int base = r * RANGE;
    int lim = min(n - base, RANGE);
    int start = offs[(size_t)r * JC];
    int end = (r + 1 < R) ? offs[(size_t)(r + 1) * JC] : offs[(size_t)R * JC];
    for (int i = threadIdx.x; i < RANGE; i += blockDim.x) indeg[i] = 0;
    __syncthreads();
    // pass 1: count per-node (skip pad dummies dl>=RANGE); track placed count
    int placed0 = 0;
    for (int i = start + threadIdx.x; i < end; i += blockDim.x) {
        unsigned dl = recs[i].x >> 17;
        if (dl < RANGE) { atomicAdd(&indeg[dl], 1); placed0++; }
    }
    __syncthreads();
    // parallel Hillis-Steele inclusive scan -> pre[1..RANGE], pre[0]=0
    if (threadIdx.x < RANGE) pre[threadIdx.x + 1] = indeg[threadIdx.x];
    if (threadIdx.x == 0) pre[0] = 0;
    __syncthreads();
    for (int off = 1; off < RANGE; off <<= 1) {
        int v = 0;
        if (threadIdx.x < RANGE) {
            int idx = threadIdx.x + 1;
            if (idx > off) v = pre[idx - off];
        }
        __syncthreads();
        if (threadIdx.x < RANGE) pre[threadIdx.x + 1] += v;
        __syncthreads();
    }
    if (threadIdx.x < RANGE) cur[threadIdx.x] = pre[threadIdx.x];
    __syncthreads();
    // pass 2: place real records into sorted LDS buffer (re-read is L2-hot)
    bool ovf = pre[RANGE] > CAP;
    if (!ovf) {
        for (int i = start + threadIdx.x; i < end; i += blockDim.x) {
            uint2 rec = recs[i];
            unsigned dl = rec.x >> 17;
            if (dl < RANGE) {
                int pos = atomicAdd(&cur[(int)dl], 1);
                srec[pos] = make_uint2(rec.x & 0x1FFFFu, rec.y);
            }
        }
    }
    __syncthreads();
    // gather: 4 lanes per node, 16B bf16 chunks, register accumulation
    int node = threadIdx.x >> 2;
    int c = threadIdx.x & 3;
    if (node >= lim) return;
    int p0i = pre[node];
    int cnt = pre[node + 1] - p0i;
    float a0 = 0.f, a1 = 0.f, a2 = 0.f, a3 = 0.f, a4 = 0.f, a5 = 0.f, a6 = 0.f, a7 = 0.f;
    if (!ovf) {
        int i = 0;
        for (; i + 2 <= cnt; i += 2) {
            uint2 q0 = srec[p0i + i];
            uint2 q1 = srec[p0i + i + 1];
            uint4 b0 = ((const uint4*)(featb + (size_t)q0.x * D))[c];
            uint4 b1 = ((const uint4*)(featb + (size_t)q1.x * D))[c];
            float w0 = __uint_as_float(q0.y);
            float w1 = __uint_as_float(q1.y);
            a0 += __uint_as_float(b0.x << 16) * w0 + __uint_as_float(b1.x << 16) * w1;
            a1 += __uint_as_float(b0.x & 0xFFFF0000u) * w0 + __uint_as_float(b1.x & 0xFFFF0000u) * w1;
            a2 += __uint_as_float(b0.y << 16) * w0 + __uint_as_float(b1.y << 16) * w1;
            a3 += __uint_as_float(b0.y & 0xFFFF0000u) * w0 + __uint_as_float(b1.y & 0xFFFF0000u) * w1;
            a4 += __uint_as_float(b0.z << 16) * w0 + __uint_as_float(b1.z << 16) * w1;
            a5 += __uint_as_float(b0.z & 0xFFFF0000u) * w0 + __uint_as_float(b1.z & 0xFFFF0000u) * w1;
            a6 += __uint_as_float(b0.w << 16) * w0 + __uint_as_float(b1.w << 16) * w1;
            a7 += __uint_as_float(b0.w & 0xFFFF0000u) * w0 + __uint_as_float(b1.w & 0xFFFF0000u) * w1;
        }
        if (i < cnt) {
            uint2 q = srec[p0i + i];
            uint4 b = ((const uint4*)(featb + (size_t)q.x * D))[c];
            float w = __uint_as_float(q.y);
            a0 += __uint_as_float(b.x << 16) * w;
            a1 += __uint_as_float(b.x & 0xFFFF0000u) * w;
            a2 += __uint_as_float(b.y << 16) * w;
            a3 += __uint_as_float(b.y & 0xFFFF0000u) * w;
            a4 += __uint_as_float(b.z << 16) * w;
            a5 += __uint_as_float(b.z & 0xFFFF0000u) * w;
            a6 += __uint_as_float(b.w << 16) * w;
            a7 += __uint_as_float(b.w & 0xFFFF0000u) * w;
        }
    } else {
        // overflow fallback: direct scan of global records (statistically never)
        for (int k = start; k < end; k++) {
            uint2 rec = recs[k];
            if ((rec.x >> 17) == (unsigned)node) {
                uint4 b = ((const uint4*)(featb + (size_t)(rec.x & 0x1FFFFu) * D))[c];
                float w = __uint_as_float(rec.y);
                a0 += __uint_as_float(b.x << 16) * w;
                a1 += __uint_as_float(b.x & 0xFFFF0000u) * w;
                a2 += __uint_as_float(b.y << 16) * w;
                a3 += __uint_as_float(b.y & 0xFFFF0000u) * w;
                a4 += __uint_as_float(b.z << 16) * w;
                a5 += __uint_as_float(b.z & 0xFFFF0000u) * w;
                a6 += __uint_as_float(b.w << 16) * w;
                a7 += __uint_as_float(b.w & 0xFFFF0000u) * w;
            }
        }
    }
    float dn = rsqrtf((float)max(cnt, 1));
    const float4* fr = (const float4*)(feat + (size_t)(base + node) * D);
    float4 fA = fr[c * 2];
    float4 fB = fr[c * 2 + 1];
    float v = fabsf(fA.x - a0 * dn) + fabsf(fA.y - a1 * dn) +
              fabsf(fA.z - a2 * dn) + fabsf(fA.w - a3 * dn) +
              fabsf(fB.x - a4 * dn) + fabsf(fB.y - a5 * dn) +
              fabsf(fB.z - a6 * dn) + fabsf(fB.w - a7 * dn);
    v += __shfl_xor(v, 1, 4);
    v += __shfl_xor(v, 2, 4);
    if (c == 0) out[base + node] = v;
}

extern "C" void kernel_launch(void* const* d_in, const int* in_sizes, int n_in,
                              void* d_out, int out_size, void* d_ws, size_t ws_size,
                              hipStream_t stream) {
    const float* feat   = (const float*)d_in[0];
    const float* e_feat = (const float*)d_in[1];
    const int*   src    = (const int*)d_in[2];
    const int*   dst    = (const int*)d_in[3];
    const int E = in_sizes[2];
    const int n = in_sizes[0] / D;
    float* out = (float*)d_out;

    const int R = (n + RANGE - 1) / RANGE;              // 782
    const int chunk = (((E + JC - 1) / JC) + 1) & ~1;   // even chunk -> int2 pairs never split
    const int total = 2 * R * JC + 1;                   // +1 grand-total slot

    // ws layout (32B-aligned regions; capacities include max padding):
    //   cnt[total] | offs[total] | blockSums[256] |
    //   recs[E + PAD_D*R*JC] uint2 | recsS[E + PAD_S*R*JC] uint | featb[n*D] ushort
    size_t recsCap  = (size_t)E + (size_t)(PAD_D - 1) * R * JC;
    size_t recsSCap = (size_t)E + (size_t)(PAD_S - 1) * R * JC;
    char* p = (char*)d_ws;
    int* cnt       = (int*)p;   p += ((size_t)total * 4 + 31) & ~(size_t)31;
    int* offs      = (int*)p;   p += ((size_t)total * 4 + 31) & ~(size_t)31;
    int* blockSums = (int*)p;   p += 256 * 4;
    uint2* recs    = (uint2*)p; p += (recsCap * 8 + 31) & ~(size_t)31;
    unsigned int* recsS = (unsigned int*)p; p += (recsSCap * 4 + 31) & ~(size_t)31;
    unsigned short* featb = (unsigned short*)p;

    count_kernel<<<JC, 512, 0, stream>>>(src, dst, cnt, E, R, chunk);

    int nb = (total + SCAN_CHUNK - 1) / SCAN_CHUNK;  // 196 (<=256)
    scan_part<<<nb, 256, 0, stream>>>(cnt, offs, blockSums, total);
    scan_top<<<1, 256, 0, stream>>>(blockSums, nb);
    scan_add<<<(total + 255) / 256, 256, 0, stream>>>(offs, blockSums, total);

    reorder_kernel<<<JC, 512, 0, stream>>>(src, dst, e_feat, offs, recsS, recs, E, R, chunk);

    srcnorm_convert<<<R, 256, 0, stream>>>(recsS, offs, feat, featb, E, n, R);

    gather_kernel<<<R, 512, 0, stream>>>(feat, featb, recs, offs, out, E, n, R);
}

// Round 11
// 160.053 us; speedup vs baseline: 1.1338x; 1.1338x over previous
//
#include <hip/hip_runtime.h>

#define D 32
#define RANGE 128        // nodes per range; R = ceil(n/RANGE) = 782
#define RMAX 800         // LDS counter capacity for coarse passes
#define JC 512           // edge chunks for count/reorder passes
#define CHUNKMAX 3200    // LDS record capacity per reorder block (chunk = 3126)
#define SCAN_CHUNK 4096  // scan: 256 threads x 16 elems
#define CAP 2560         // gather LDS sorted-record capacity (mean 2048, +11 sigma)

// ---- K1: per-(range,chunk) coarse counts for dst AND src in one pass. ----
__global__ __launch_bounds__(512) void count_kernel(
        const int* __restrict__ src, const int* __restrict__ dst,
        int* __restrict__ cnt, int E, int R, int chunk) {
    __shared__ int cd[RMAX];
    __shared__ int cs[RMAX];
    int j = blockIdx.x;
    for (int i = threadIdx.x; i < R; i += blockDim.x) { cd[i] = 0; cs[i] = 0; }
    __syncthreads();
    int e0 = j * chunk, e1 = min(E, e0 + chunk);
    for (int e = e0 + 2 * threadIdx.x; e < e1; e += 2 * blockDim.x) {
        if (e + 1 < e1) {
            int2 s2 = *(const int2*)(src + e);
            int2 d2 = *(const int2*)(dst + e);
            atomicAdd(&cd[d2.x >> 7], 1);
            atomicAdd(&cd[d2.y >> 7], 1);
            atomicAdd(&cs[s2.x >> 7], 1);
            atomicAdd(&cs[s2.y >> 7], 1);
        } else {
            atomicAdd(&cd[dst[e] >> 7], 1);
            atomicAdd(&cs[src[e] >> 7], 1);
        }
    }
    __syncthreads();
    // layout: cnt[r*JC + j] (dst) ; cnt[(R+r)*JC + j] (src) — r-major so the
    // scan produces range-contiguous segments
    for (int i = threadIdx.x; i < R; i += blockDim.x) {
        cnt[(size_t)i * JC + j]       = cd[i];
        cnt[(size_t)(R + i) * JC + j] = cs[i];
    }
    if (j == 0 && threadIdx.x == 0) cnt[(size_t)2 * R * JC] = 0;  // grand-total slot
}

// ---- hierarchical exclusive scan over 2*R*JC+1 counts ----
__global__ void scan_part(const int* __restrict__ deg, int* __restrict__ offsets,
                          int* __restrict__ blockSums, int n) {
    __shared__ int lds[256];
    int t = threadIdx.x;
    int base = blockIdx.x * SCAN_CHUNK + t * 16;
    int v[16];
    int tsum = 0;
#pragma unroll
    for (int i = 0; i < 16; i++) {
        int idx = base + i;
        int x = (idx < n) ? deg[idx] : 0;
        v[i] = tsum;
        tsum += x;
    }
    lds[t] = tsum;
    __syncthreads();
    for (int off = 1; off < 256; off <<= 1) {
        int val = (t >= off) ? lds[t - off] : 0;
        __syncthreads();
        lds[t] += val;
        __syncthreads();
    }
    int texcl = (t == 0) ? 0 : lds[t - 1];
    if (t == 255) blockSums[blockIdx.x] = lds[255];
#pragma unroll
    for (int i = 0; i < 16; i++) {
        int idx = base + i;
        if (idx < n) offsets[idx] = texcl + v[i];
    }
}

__global__ void scan_top(int* __restrict__ blockSums, int nb) {
    __shared__ int lds[256];
    int t = threadIdx.x;
    lds[t] = (t < nb) ? blockSums[t] : 0;
    __syncthreads();
    for (int off = 1; off < 256; off <<= 1) {
        int val = (t >= off) ? lds[t - off] : 0;
        __syncthreads();
        lds[t] += val;
        __syncthreads();
    }
    if (t < nb) blockSums[t] = (t == 0) ? 0 : lds[t - 1];
}

__global__ void scan_add(int* __restrict__ offsets, const int* __restrict__ blockSums, int n) {
    int i = blockIdx.x * blockDim.x + threadIdx.x;
    if (i < n) offsets[i] += blockSums[i / SCAN_CHUNK];
}

// ---- K2: LDS counting-sort per chunk, then COALESCED sequential write-out. ----
// dst rec = (s | dl<<17, ef_masked). src rec = s (4B, range = s>>7).
__global__ __launch_bounds__(512) void reorder_kernel(
        const int* __restrict__ src, const int* __restrict__ dst,
        const float* __restrict__ ef, const int* __restrict__ offs,
        unsigned int* __restrict__ recsS, uint2* __restrict__ recs,
        int E, int R, int chunk) {
    __shared__ uint2 sd[CHUNKMAX];            // 25.6 KB sorted dst records
    __shared__ unsigned short rd[CHUNKMAX];   // 6.4 KB range per dst record
    __shared__ unsigned int ss_[CHUNKMAX];    // 12.8 KB sorted src ids
    __shared__ int cd[RMAX];                  // counts (later: write bases)
    __shared__ int cs[RMAX];
    __shared__ int curD[RMAX];                // scan / cursors
    __shared__ int curS[RMAX];
    int j = blockIdx.x;
    int t = threadIdx.x;
    int e0 = j * chunk, e1 = min(E, e0 + chunk);
    int cntE = e1 - e0;
    for (int i = t; i < RMAX; i += blockDim.x) { cd[i] = 0; cs[i] = 0; }
    __syncthreads();
    // pass 1: count per-range
    for (int e = e0 + 2 * t; e < e1; e += 2 * blockDim.x) {
        if (e + 1 < e1) {
            int2 s2 = *(const int2*)(src + e);
            int2 d2 = *(const int2*)(dst + e);
            atomicAdd(&cd[d2.x >> 7], 1);
            atomicAdd(&cd[d2.y >> 7], 1);
            atomicAdd(&cs[s2.x >> 7], 1);
            atomicAdd(&cs[s2.y >> 7], 1);
        } else {
            atomicAdd(&cd[dst[e] >> 7], 1);
            atomicAdd(&cs[src[e] >> 7], 1);
        }
    }
    __syncthreads();
    // Hillis-Steele inclusive scan of cd,cs into curD,curS (RMAX entries, 512 thr)
    {
        int i1 = t + 512;
        curD[t] = cd[t];
        curS[t] = cs[t];
        if (i1 < RMAX) { curD[i1] = cd[i1]; curS[i1] = cs[i1]; }
        __syncthreads();
        for (int off = 1; off < RMAX; off <<= 1) {
            int vD0 = (t >= off) ? curD[t - off] : 0;
            int vS0 = (t >= off) ? curS[t - off] : 0;
            int vD1 = 0, vS1 = 0;
            if (i1 < RMAX && i1 >= off) { vD1 = curD[i1 - off]; vS1 = curS[i1 - off]; }
            __syncthreads();
            curD[t] += vD0;
            curS[t] += vS0;
            if (i1 < RMAX) { curD[i1] += vD1; curS[i1] += vS1; }
            __syncthreads();
        }
        // exclusive cursors
        curD[t] -= cd[t];
        curS[t] -= cs[t];
        if (i1 < RMAX) { curD[i1] -= cd[i1]; curS[i1] -= cs[i1]; }
        __syncthreads();
    }
    // pass 2: place into LDS sorted by range
    for (int e = e0 + t; e < e1; e += blockDim.x) {
        int s = src[e], d = dst[e];
        int r = d >> 7;
        float w = (s == d) ? 0.0f : ef[e];
        int pos = atomicAdd(&curD[r], 1);
        sd[pos] = make_uint2((unsigned)s | ((unsigned)(d & (RANGE - 1)) << 17),
                             __float_as_uint(w));
        rd[pos] = (unsigned short)r;
        int rs = s >> 7;
        int ps = atomicAdd(&curS[rs], 1);
        ss_[ps] = (unsigned)s;
    }
    __syncthreads();
    // write bases: global segment start minus local segment start
    int srcBase = offs[(size_t)R * JC];
    for (int i = t; i < R; i += blockDim.x) {
        cd[i] = offs[(size_t)i * JC + j] - (curD[i] - cd[i]);
        cs[i] = (offs[(size_t)(R + i) * JC + j] - srcBase) - (curS[i] - cs[i]);
    }
    __syncthreads();
    // coalesced write-out: consecutive i -> consecutive addresses within a segment
    for (int i = t; i < cntE; i += blockDim.x) {
        recs[cd[rd[i]] + i] = sd[i];
        unsigned s = ss_[i];
        recsS[cs[s >> 7] + i] = s;
    }
}

// ---- K3: fused out-degree count + pre-scaled bf16 feature rows. ----
__device__ __forceinline__ unsigned short f2bf(float x) {
    unsigned u = __float_as_uint(x);
    u += 0x7FFFu + ((u >> 16) & 1u);
    return (unsigned short)(u >> 16);
}

__global__ void srcnorm_convert(const unsigned int* __restrict__ recsS,
                                const int* __restrict__ offs, const float* __restrict__ feat,
                                unsigned short* __restrict__ featb, int E, int n, int R) {
    __shared__ int cnt[RANGE];
    int r = blockIdx.x;
    int base = r * RANGE;
    int lim = min(n - base, RANGE);
    for (int i = threadIdx.x; i < RANGE; i += blockDim.x) cnt[i] = 0;
    __syncthreads();
    int srcBase = offs[(size_t)R * JC];
    int start = offs[(size_t)(R + r) * JC] - srcBase;
    int end = ((r + 1 < R) ? offs[(size_t)(R + r + 1) * JC]
                           : offs[(size_t)2 * R * JC]) - srcBase;
    for (int i = start + threadIdx.x; i < end; i += blockDim.x)
        atomicAdd(&cnt[recsS[i] - (unsigned)base], 1);   // LDS atomic
    __syncthreads();
    int total4 = lim * 8;   // 8 float4 chunks per row
    for (int i = threadIdx.x; i < total4; i += blockDim.x) {
        int row = i >> 3;
        float sn = rsqrtf((float)max(cnt[row], 1));
        float4 f = ((const float4*)(feat + (size_t)(base + row) * D))[i & 7];
        ushort4 u;
        u.x = f2bf(f.x * sn); u.y = f2bf(f.y * sn);
        u.z = f2bf(f.z * sn); u.w = f2bf(f.w * sn);
        ((ushort4*)(featb + (size_t)(base + row) * D))[i & 7] = u;
    }
}

// ---- K4: per-range counting sort in LDS + per-node register gather + output. ----
__global__ __launch_bounds__(512) void gather_kernel(
        const float* __restrict__ feat, const unsigned short* __restrict__ featb,
        const uint2* __restrict__ recs, const int* __restrict__ offs,
        float* __restrict__ out, int E, int n, int R) {
    __shared__ uint2 srec[CAP];          // 20.5 KB sorted records
    __shared__ int indeg[RANGE];
    __shared__ int pre[RANGE + 1];
    __shared__ int cur[RANGE];
    int r = blockIdx.x;
    int base = r * RANGE;
    int lim = min(n - base, RANGE);
    int start = offs[(size_t)r * JC];
    int end = (r + 1 < R) ? offs[(size_t)(r + 1) * JC] : offs[(size_t)R * JC];
    for (int i = threadIdx.x; i < RANGE; i += blockDim.x) indeg[i] = 0;
    __syncthreads();
    // pass 1: count per-node
    for (int i = start + threadIdx.x; i < end; i += blockDim.x)
        atomicAdd(&indeg[(recs[i].x >> 17) & 0x1FFu], 1);
    __syncthreads();
    // parallel Hillis-Steele inclusive scan -> pre[1..RANGE], pre[0]=0
    if (threadIdx.x < RANGE) pre[threadIdx.x + 1] = indeg[threadIdx.x];
    if (threadIdx.x == 0) pre[0] = 0;
    __syncthreads();
    for (int off = 1; off < RANGE; off <<= 1) {
        int v = 0;
        if (threadIdx.x < RANGE) {
            int idx = threadIdx.x + 1;
            if (idx > off) v = pre[idx - off];
        }
        __syncthreads();
        if (threadIdx.x < RANGE) pre[threadIdx.x + 1] += v;
        __syncthreads();
    }
    if (threadIdx.x < RANGE) cur[threadIdx.x] = pre[threadIdx.x];
    __syncthreads();
    bool ovf = pre[RANGE] > CAP;
    // pass 2: place into sorted LDS buffer (re-read is L2-hot)
    if (!ovf) {
        for (int i = start + threadIdx.x; i < end; i += blockDim.x) {
            uint2 rec = recs[i];
            int dl = (rec.x >> 17) & 0x1FFu;
            int pos = atomicAdd(&cur[dl], 1);
            srec[pos] = make_uint2(rec.x & 0x1FFFFu, rec.y);
        }
    }
    __syncthreads();
    // gather: 4 lanes per node, 16B bf16 chunks, register accumulation
    int node = threadIdx.x >> 2;
    int c = threadIdx.x & 3;
    if (node >= lim) return;
    int p0i = pre[node];
    int cnt = pre[node + 1] - p0i;
    float a0 = 0.f, a1 = 0.f, a2 = 0.f, a3 = 0.f, a4 = 0.f, a5 = 0.f, a6 = 0.f, a7 = 0.f;
    if (!ovf) {
        int i = 0;
        for (; i + 2 <= cnt; i += 2) {
            uint2 q0 = srec[p0i + i];
            uint2 q1 = srec[p0i + i + 1];
            uint4 b0 = ((const uint4*)(featb + (size_t)q0.x * D))[c];
            uint4 b1 = ((const uint4*)(featb + (size_t)q1.x * D))[c];
            float w0 = __uint_as_float(q0.y);
            float w1 = __uint_as_float(q1.y);
            a0 += __uint_as_float(b0.x << 16) * w0 + __uint_as_float(b1.x << 16) * w1;
            a1 += __uint_as_float(b0.x & 0xFFFF0000u) * w0 + __uint_as_float(b1.x & 0xFFFF0000u) * w1;
            a2 += __uint_as_float(b0.y << 16) * w0 + __uint_as_float(b1.y << 16) * w1;
            a3 += __uint_as_float(b0.y & 0xFFFF0000u) * w0 + __uint_as_float(b1.y & 0xFFFF0000u) * w1;
            a4 += __uint_as_float(b0.z << 16) * w0 + __uint_as_float(b1.z << 16) * w1;
            a5 += __uint_as_float(b0.z & 0xFFFF0000u) * w0 + __uint_as_float(b1.z & 0xFFFF0000u) * w1;
            a6 += __uint_as_float(b0.w << 16) * w0 + __uint_as_float(b1.w << 16) * w1;
            a7 += __uint_as_float(b0.w & 0xFFFF0000u) * w0 + __uint_as_float(b1.w & 0xFFFF0000u) * w1;
        }
        if (i < cnt) {
            uint2 q = srec[p0i + i];
            uint4 b = ((const uint4*)(featb + (size_t)q.x * D))[c];
            float w = __uint_as_float(q.y);
            a0 += __uint_as_float(b.x << 16) * w;
            a1 += __uint_as_float(b.x & 0xFFFF0000u) * w;
            a2 += __uint_as_float(b.y << 16) * w;
            a3 += __uint_as_float(b.y & 0xFFFF0000u) * w;
            a4 += __uint_as_float(b.z << 16) * w;
            a5 += __uint_as_float(b.z & 0xFFFF0000u) * w;
            a6 += __uint_as_float(b.w << 16) * w;
            a7 += __uint_as_float(b.w & 0xFFFF0000u) * w;
        }
    } else {
        // overflow fallback: direct scan of global records (statistically never)
        for (int k = start; k < end; k++) {
            uint2 rec = recs[k];
            if (((rec.x >> 17) & 0x1FFu) == (unsigned)node) {
                uint4 b = ((const uint4*)(featb + (size_t)(rec.x & 0x1FFFFu) * D))[c];
                float w = __uint_as_float(rec.y);
                a0 += __uint_as_float(b.x << 16) * w;
                a1 += __uint_as_float(b.x & 0xFFFF0000u) * w;
                a2 += __uint_as_float(b.y << 16) * w;
                a3 += __uint_as_float(b.y & 0xFFFF0000u) * w;
                a4 += __uint_as_float(b.z << 16) * w;
                a5 += __uint_as_float(b.z & 0xFFFF0000u) * w;
                a6 += __uint_as_float(b.w << 16) * w;
                a7 += __uint_as_float(b.w & 0xFFFF0000u) * w;
            }
        }
    }
    float dn = rsqrtf((float)max(cnt, 1));
    const float4* fr = (const float4*)(feat + (size_t)(base + node) * D);
    float4 fA = fr[c * 2];
    float4 fB = fr[c * 2 + 1];
    float v = fabsf(fA.x - a0 * dn) + fabsf(fA.y - a1 * dn) +
              fabsf(fA.z - a2 * dn) + fabsf(fA.w - a3 * dn) +
              fabsf(fB.x - a4 * dn) + fabsf(fB.y - a5 * dn) +
              fabsf(fB.z - a6 * dn) + fabsf(fB.w - a7 * dn);
    v += __shfl_xor(v, 1, 4);
    v += __shfl_xor(v, 2, 4);
    if (c == 0) out[base + node] = v;
}

extern "C" void kernel_launch(void* const* d_in, const int* in_sizes, int n_in,
                              void* d_out, int out_size, void* d_ws, size_t ws_size,
                              hipStream_t stream) {
    const float* feat   = (const float*)d_in[0];
    const float* e_feat = (const float*)d_in[1];
    const int*   src    = (const int*)d_in[2];
    const int*   dst    = (const int*)d_in[3];
    const int E = in_sizes[2];
    const int n = in_sizes[0] / D;
    float* out = (float*)d_out;

    const int R = (n + RANGE - 1) / RANGE;              // 782
    const int chunk = (((E + JC - 1) / JC) + 1) & ~1;   // 3126 (even, <= CHUNKMAX)
    const int total = 2 * R * JC + 1;                   // +1 grand-total slot

    // ws layout (16B-aligned):
    //   cnt[total] | offs[total] | blockSums[256] |
    //   recs[E] uint2 | recsS[E] uint | featb[n*D] ushort
    char* p = (char*)d_ws;
    int* cnt       = (int*)p;   p += ((size_t)total * 4 + 15) & ~(size_t)15;
    int* offs      = (int*)p;   p += ((size_t)total * 4 + 15) & ~(size_t)15;
    int* blockSums = (int*)p;   p += 256 * 4;
    uint2* recs    = (uint2*)p; p += ((size_t)E * 8 + 15) & ~(size_t)15;
    unsigned int* recsS = (unsigned int*)p; p += ((size_t)E * 4 + 15) & ~(size_t)15;
    unsigned short* featb = (unsigned short*)p;

    count_kernel<<<JC, 512, 0, stream>>>(src, dst, cnt, E, R, chunk);

    int nb = (total + SCAN_CHUNK - 1) / SCAN_CHUNK;  // 196 (<=256)
    scan_part<<<nb, 256, 0, stream>>>(cnt, offs, blockSums, total);
    scan_top<<<1, 256, 0, stream>>>(blockSums, nb);
    scan_add<<<(total + 255) / 256, 256, 0, stream>>>(offs, blockSums, total);

    reorder_kernel<<<JC, 512, 0, stream>>>(src, dst, e_feat, offs, recsS, recs, E, R, chunk);

    srcnorm_convert<<<R, 256, 0, stream>>>(recsS, offs, feat, featb, E, n, R);

    gather_kernel<<<R, 512, 0, stream>>>(feat, featb, recs, offs, out, E, n, R);
}

// Round 12
// 150.388 us; speedup vs baseline: 1.2066x; 1.0643x over previous
//
#include <hip/hip_runtime.h>

#define D 32
#define RANGE 128        // nodes per range; R = ceil(n/RANGE) = 782
#define RMAX 800         // LDS counter capacity (>= R)
#define JC 512           // edge chunks == blockDim of consumers' segment loops
#define CHUNKMAX 3200    // LDS record capacity per sort block (chunk = 3126)
#define CAP 2560         // gather LDS record capacity per range (mean 2048, +11 sigma)

// ---- K1: per-chunk LDS counting-sort by range; chunk-contiguous coalesced
// write-out; publishes meta[j][r] = localStart<<16 | count for both streams.
// dst rec = (s | dl<<17, ef_masked). src rec = s.
__global__ __launch_bounds__(512) void sort_chunks(
        const int* __restrict__ src, const int* __restrict__ dst,
        const float* __restrict__ ef,
        uint2* __restrict__ recs, unsigned* __restrict__ recsS,
        unsigned* __restrict__ metaD, unsigned* __restrict__ metaS,
        int E, int R, int chunk) {
    __shared__ uint2 sd[CHUNKMAX];           // 25.6 KB sorted dst records
    __shared__ unsigned ss_[CHUNKMAX];       // 12.8 KB sorted src ids
    __shared__ int cd[RMAX], cs[RMAX];       // per-range counts
    __shared__ int curD[RMAX], curS[RMAX];   // scan / cursors
    int j = blockIdx.x, t = threadIdx.x;
    int e0 = j * chunk, e1 = min(E, e0 + chunk), cntE = e1 - e0;
    for (int i = t; i < RMAX; i += 512) { cd[i] = 0; cs[i] = 0; }
    __syncthreads();
    // pass 1: count per-range
    for (int e = e0 + 2 * t; e < e1; e += 1024) {
        if (e + 1 < e1) {
            int2 s2 = *(const int2*)(src + e);
            int2 d2 = *(const int2*)(dst + e);
            atomicAdd(&cd[d2.x >> 7], 1);
            atomicAdd(&cd[d2.y >> 7], 1);
            atomicAdd(&cs[s2.x >> 7], 1);
            atomicAdd(&cs[s2.y >> 7], 1);
        } else {
            atomicAdd(&cd[dst[e] >> 7], 1);
            atomicAdd(&cs[src[e] >> 7], 1);
        }
    }
    __syncthreads();
    // Hillis-Steele inclusive scan (RMAX entries, 2 per thread) -> exclusive cursors
    {
        int i1 = t + 512;
        curD[t] = cd[t]; curS[t] = cs[t];
        if (i1 < RMAX) { curD[i1] = cd[i1]; curS[i1] = cs[i1]; }
        __syncthreads();
        for (int off = 1; off < RMAX; off <<= 1) {
            int vD0 = (t >= off) ? curD[t - off] : 0;
            int vS0 = (t >= off) ? curS[t - off] : 0;
            int vD1 = 0, vS1 = 0;
            if (i1 < RMAX && i1 >= off) { vD1 = curD[i1 - off]; vS1 = curS[i1 - off]; }
            __syncthreads();
            curD[t] += vD0; curS[t] += vS0;
            if (i1 < RMAX) { curD[i1] += vD1; curS[i1] += vS1; }
            __syncthreads();
        }
        curD[t] -= cd[t]; curS[t] -= cs[t];
        if (i1 < RMAX) { curD[i1] -= cd[i1]; curS[i1] -= cs[i1]; }
        __syncthreads();
    }
    // pass 2: place into LDS sorted by range
    for (int e = e0 + t; e < e1; e += 512) {
        int s = src[e], d = dst[e];
        float w = (s == d) ? 0.0f : ef[e];
        int pos = atomicAdd(&curD[d >> 7], 1);
        sd[pos] = make_uint2((unsigned)s | ((unsigned)(d & (RANGE - 1)) << 17),
                             __float_as_uint(w));
        int ps = atomicAdd(&curS[s >> 7], 1);
        ss_[ps] = (unsigned)s;
    }
    __syncthreads();
    // coalesced chunk-contiguous write-out
    size_t baseE = (size_t)j * chunk;
    for (int i = t; i < cntE; i += 512) {
        recs[baseE + i] = sd[i];
        recsS[baseE + i] = ss_[i];
    }
    // meta (start and count both <= 3126, fit 16 bits); curD now == start+count
    for (int i = t; i < R; i += 512) {
        metaD[(size_t)j * R + i] = ((unsigned)(curD[i] - cd[i]) << 16) | (unsigned)cd[i];
        metaS[(size_t)j * R + i] = ((unsigned)(curS[i] - cs[i]) << 16) | (unsigned)cs[i];
    }
}

// ---- K2: per-range out-degree count from src segments + pre-scaled bf16 rows. ----
__device__ __forceinline__ unsigned short f2bf(float x) {
    unsigned u = __float_as_uint(x);
    u += 0x7FFFu + ((u >> 16) & 1u);
    return (unsigned short)(u >> 16);
}

__global__ __launch_bounds__(512) void srcnorm_convert(
        const unsigned* __restrict__ recsS, const unsigned* __restrict__ metaS,
        const float* __restrict__ feat, unsigned short* __restrict__ featb,
        int n, int R, int chunk) {
    __shared__ int cnt[RANGE];
    int r = blockIdx.x, t = threadIdx.x;
    int base = r * RANGE, lim = min(n - base, RANGE);
    if (t < RANGE) cnt[t] = 0;
    __syncthreads();
    // thread t handles chunk j == t (JC == 512 == blockDim)
    unsigned m = metaS[(size_t)t * R + r];
    int st = m >> 16, c = m & 0xFFFFu;
    const unsigned* p = recsS + (size_t)t * chunk + st;
    for (int k = 0; k < c; k++) atomicAdd(&cnt[p[k] - (unsigned)base], 1);
    __syncthreads();
    int total4 = lim * 8;   // 8 float4 chunks per row
    for (int i = t; i < total4; i += 512) {
        int row = i >> 3;
        float sn = rsqrtf((float)max(cnt[row], 1));
        float4 f = ((const float4*)(feat + (size_t)(base + row) * D))[i & 7];
        ushort4 u;
        u.x = f2bf(f.x * sn); u.y = f2bf(f.y * sn);
        u.z = f2bf(f.z * sn); u.w = f2bf(f.w * sn);
        ((ushort4*)(featb + (size_t)(base + row) * D))[i & 7] = u;
    }
}

// ---- K3: per-range segment collect -> LDS node-sort -> register gather + output. ----
__global__ __launch_bounds__(512) void gather_kernel(
        const float* __restrict__ feat, const unsigned short* __restrict__ featb,
        const uint2* __restrict__ recs, const unsigned* __restrict__ metaD,
        float* __restrict__ out, int n, int R, int chunk) {
    __shared__ uint2 raw[CAP];           // 20.5 KB segment-appended records
    __shared__ uint2 srec[CAP];          // 20.5 KB node-sorted records
    __shared__ int segpre[JC + 1];       // 2 KB segment-count prefix
    __shared__ int indeg[RANGE];
    __shared__ int pre[RANGE + 1];
    __shared__ int cur[RANGE];
    int r = blockIdx.x, t = threadIdx.x;
    int base = r * RANGE, lim = min(n - base, RANGE);
    unsigned m = metaD[(size_t)t * R + r];    // thread t owns chunk j == t
    int st = m >> 16, c = m & 0xFFFFu;
    segpre[t + 1] = c;
    if (t == 0) segpre[0] = 0;
    if (t < RANGE) indeg[t] = 0;
    __syncthreads();
    // Hillis-Steele inclusive scan over 512 segment counts
    for (int off = 1; off < JC; off <<= 1) {
        int v = (t + 1 > off) ? segpre[t + 1 - off] : 0;
        __syncthreads();
        segpre[t + 1] += v;
        __syncthreads();
    }
    int total = segpre[JC];
    bool ovf = total > CAP;
    // collect my segment into raw + count in-degrees
    const uint2* p = recs + (size_t)t * chunk + st;
    if (!ovf) {
        int dp = segpre[t];
        for (int k = 0; k < c; k++) {
            uint2 rec = p[k];
            raw[dp + k] = rec;
            atomicAdd(&indeg[rec.x >> 17], 1);
        }
    } else {
        for (int k = 0; k < c; k++) atomicAdd(&indeg[p[k].x >> 17], 1);
    }
    __syncthreads();
    // node-count prefix scan (RANGE = 128)
    if (t < RANGE) pre[t + 1] = indeg[t];
    if (t == 0) pre[0] = 0;
    __syncthreads();
    for (int off = 1; off < RANGE; off <<= 1) {
        int v = 0;
        if (t < RANGE) { int idx = t + 1; if (idx > off) v = pre[idx - off]; }
        __syncthreads();
        if (t < RANGE) pre[t + 1] += v;
        __syncthreads();
    }
    if (t < RANGE) cur[t] = pre[t];
    __syncthreads();
    // sort raw -> srec by node
    if (!ovf) {
        for (int i = t; i < total; i += 512) {
            uint2 rec = raw[i];
            int dl = rec.x >> 17;
            int pos = atomicAdd(&cur[dl], 1);
            srec[pos] = make_uint2(rec.x & 0x1FFFFu, rec.y);
        }
    }
    __syncthreads();
    // gather: 4 lanes per node, 16B bf16 chunks, register accumulation
    int node = t >> 2;
    int cch = t & 3;
    if (node >= lim) return;
    int p0i = pre[node];
    int cnt = pre[node + 1] - p0i;
    float a0 = 0.f, a1 = 0.f, a2 = 0.f, a3 = 0.f, a4 = 0.f, a5 = 0.f, a6 = 0.f, a7 = 0.f;
    if (!ovf) {
        int i = 0;
        for (; i + 2 <= cnt; i += 2) {
            uint2 q0 = srec[p0i + i];
            uint2 q1 = srec[p0i + i + 1];
            uint4 b0 = ((const uint4*)(featb + (size_t)q0.x * D))[cch];
            uint4 b1 = ((const uint4*)(featb + (size_t)q1.x * D))[cch];
            float w0 = __uint_as_float(q0.y);
            float w1 = __uint_as_float(q1.y);
            a0 += __uint_as_float(b0.x << 16) * w0 + __uint_as_float(b1.x << 16) * w1;
            a1 += __uint_as_float(b0.x & 0xFFFF0000u) * w0 + __uint_as_float(b1.x & 0xFFFF0000u) * w1;
            a2 += __uint_as_float(b0.y << 16) * w0 + __uint_as_float(b1.y << 16) * w1;
            a3 += __uint_as_float(b0.y & 0xFFFF0000u) * w0 + __uint_as_float(b1.y & 0xFFFF0000u) * w1;
            a4 += __uint_as_float(b0.z << 16) * w0 + __uint_as_float(b1.z << 16) * w1;
            a5 += __uint_as_float(b0.z & 0xFFFF0000u) * w0 + __uint_as_float(b1.z & 0xFFFF0000u) * w1;
            a6 += __uint_as_float(b0.w << 16) * w0 + __uint_as_float(b1.w << 16) * w1;
            a7 += __uint_as_float(b0.w & 0xFFFF0000u) * w0 + __uint_as_float(b1.w & 0xFFFF0000u) * w1;
        }
        if (i < cnt) {
            uint2 q = srec[p0i + i];
            uint4 b = ((const uint4*)(featb + (size_t)q.x * D))[cch];
            float w = __uint_as_float(q.y);
            a0 += __uint_as_float(b.x << 16) * w;
            a1 += __uint_as_float(b.x & 0xFFFF0000u) * w;
            a2 += __uint_as_float(b.y << 16) * w;
            a3 += __uint_as_float(b.y & 0xFFFF0000u) * w;
            a4 += __uint_as_float(b.z << 16) * w;
            a5 += __uint_as_float(b.z & 0xFFFF0000u) * w;
            a6 += __uint_as_float(b.w << 16) * w;
            a7 += __uint_as_float(b.w & 0xFFFF0000u) * w;
        }
    } else {
        // overflow fallback: direct scan of all segments (statistically never taken)
        for (int j = 0; j < JC; j++) {
            unsigned mm = metaD[(size_t)j * R + r];
            const uint2* pp = recs + (size_t)j * chunk + (mm >> 16);
            int cc = mm & 0xFFFFu;
            for (int k = 0; k < cc; k++) {
                uint2 rec = pp[k];
                if ((int)(rec.x >> 17) == node) {
                    uint4 b = ((const uint4*)(featb + (size_t)(rec.x & 0x1FFFFu) * D))[cch];
                    float w = __uint_as_float(rec.y);
                    a0 += __uint_as_float(b.x << 16) * w;
                    a1 += __uint_as_float(b.x & 0xFFFF0000u) * w;
                    a2 += __uint_as_float(b.y << 16) * w;
                    a3 += __uint_as_float(b.y & 0xFFFF0000u) * w;
                    a4 += __uint_as_float(b.z << 16) * w;
                    a5 += __uint_as_float(b.z & 0xFFFF0000u) * w;
                    a6 += __uint_as_float(b.w << 16) * w;
                    a7 += __uint_as_float(b.w & 0xFFFF0000u) * w;
                }
            }
        }
    }
    float dn = rsqrtf((float)max(cnt, 1));
    const float4* fr = (const float4*)(feat + (size_t)(base + node) * D);
    float4 fA = fr[cch * 2];
    float4 fB = fr[cch * 2 + 1];
    float v = fabsf(fA.x - a0 * dn) + fabsf(fA.y - a1 * dn) +
              fabsf(fA.z - a2 * dn) + fabsf(fA.w - a3 * dn) +
              fabsf(fB.x - a4 * dn) + fabsf(fB.y - a5 * dn) +
              fabsf(fB.z - a6 * dn) + fabsf(fB.w - a7 * dn);
    v += __shfl_xor(v, 1, 4);
    v += __shfl_xor(v, 2, 4);
    if (cch == 0) out[base + node] = v;
}

extern "C" void kernel_launch(void* const* d_in, const int* in_sizes, int n_in,
                              void* d_out, int out_size, void* d_ws, size_t ws_size,
                              hipStream_t stream) {
    const float* feat   = (const float*)d_in[0];
    const float* e_feat = (const float*)d_in[1];
    const int*   src    = (const int*)d_in[2];
    const int*   dst    = (const int*)d_in[3];
    const int E = in_sizes[2];
    const int n = in_sizes[0] / D;
    float* out = (float*)d_out;

    const int R = (n + RANGE - 1) / RANGE;              // 782
    const int chunk = (((E + JC - 1) / JC) + 1) & ~1;   // 3126 (even, <= CHUNKMAX, < 65536)

    // ws layout (16B-aligned; every cell written before read — no memset needed):
    //   recs[JC*chunk] uint2 | recsS[JC*chunk] uint |
    //   metaD[JC*R] uint | metaS[JC*R] uint | featb[n*D] ushort
    char* p = (char*)d_ws;
    uint2* recs    = (uint2*)p;    p += ((size_t)JC * chunk * 8 + 15) & ~(size_t)15;
    unsigned* recsS = (unsigned*)p; p += ((size_t)JC * chunk * 4 + 15) & ~(size_t)15;
    unsigned* metaD = (unsigned*)p; p += ((size_t)JC * R * 4 + 15) & ~(size_t)15;
    unsigned* metaS = (unsigned*)p; p += ((size_t)JC * R * 4 + 15) & ~(size_t)15;
    unsigned short* featb = (unsigned short*)p;

    sort_chunks<<<JC, 512, 0, stream>>>(src, dst, e_feat, recs, recsS, metaD, metaS,
                                        E, R, chunk);

    srcnorm_convert<<<R, 512, 0, stream>>>(recsS, metaS, feat, featb, n, R, chunk);

    gather_kernel<<<R, 512, 0, stream>>>(feat, featb, recs, metaD, out, n, R, chunk);
}